// Round 1
// 276.610 us; speedup vs baseline: 1.0790x; 1.0790x over previous
//
#include <hip/hip_runtime.h>
#include <hip/hip_fp16.h>
#include <math.h>

#define DIM 128
#define NN 50000
#define NE 600000
#define EPS 1e-5f
#define CAP 64   // per-dst bucket capacity; P(Poisson(12) > 64) ~ 5e-26

struct H8 { __half2 h[4]; };   // 16 B of fp16 channels
struct F8 { float4 a, b; };    // 32 B of fp32 channels

typedef _Float16 f16x8 __attribute__((ext_vector_type(8)));
typedef float    f32x4 __attribute__((ext_vector_type(4)));

// fast GELU (tanh form), |err| < ~7e-4 absolute
__device__ __forceinline__ float gelu_fast(float x) {
    const float c1 = 2.3022085f;   // 0.7978845608 * 2 * log2(e)
    const float c2 = 0.1029437f;   // c1 * 0.044715
    const float x2 = x * x;
    const float z  = x * __builtin_fmaf(c2, x2, c1);
    const float u  = __builtin_amdgcn_exp2f(z);
    const float r  = __builtin_amdgcn_rcpf(1.f + u);
    return __builtin_fmaf(-x, r, x);
}

__device__ __forceinline__ float sigmoid_fast(float y) {
    const float u = __builtin_amdgcn_exp2f(-1.4426950409f * y);
    return __builtin_amdgcn_rcpf(1.f + u);
}

// ---------------------------------------------------------------------------
// Prep 1: fold BN scale into gate layer-1 weights; emit fragment-ready
// fp16 transposed weights WABth[c][k] (c=0..255 over [WA|WB], k=0..127).
// ---------------------------------------------------------------------------
__global__ __launch_bounds__(256) void k_prep_scale(
    const float* __restrict__ Wg1, const float* __restrict__ bg1,
    const float* __restrict__ bng, const float* __restrict__ bnb,
    const float* __restrict__ bnm, const float* __restrict__ bnv,
    __half* __restrict__ WABth, float* __restrict__ bA,
    float* __restrict__ w0p, float* __restrict__ w1p)
{
    const int k = blockIdx.x;      // 0..127
    const int t = threadIdx.x;     // 0..255 (fused col)
    const int c = t & 127;
    const float s = bng[c] * rsqrtf(bnv[c] + EPS);
    const float w = (t < 128) ? Wg1[k * DIM + c] : Wg1[(DIM + k) * DIM + c];
    WABth[t * DIM + k] = __float2half(w * s);
    if (k == 0 && t < 128) {
        const float tt = bnb[c] - bnm[c] * s;
        bA[c]  = bg1[c] * s + tt;
        w0p[c] = Wg1[256 * DIM + c] * s;
        w1p[c] = Wg1[257 * DIM + c] * s;
    }
}

// ---------------------------------------------------------------------------
// Prep 2: fragment-ready update weights Wct[j][k] (j=0..127, k=0..255):
//   k<128 -> Wu_top[k][j];  k>=128 -> Wpu[k-128][j] = (Wphi @ Wu_bot)[k-128][j]
// plus bpu[j] = bphi @ Wu_bot.
// ---------------------------------------------------------------------------
__global__ __launch_bounds__(128) void k_prep_wpu(
    const float* __restrict__ Wphi, const float* __restrict__ bphi,
    const float* __restrict__ Wu,
    __half* __restrict__ Wct, float* __restrict__ bpu)
{
    const int a = blockIdx.x;      // 0..127
    const int j = threadIdx.x;     // 0..127
    float acc = 0.f;
    #pragma unroll 8
    for (int k = 0; k < DIM; ++k)
        acc += Wphi[a * DIM + k] * Wu[(DIM + k) * DIM + j];
    Wct[j * 256 + a]       = __float2half(Wu[a * DIM + j]);   // top (Wu_top^T)
    Wct[j * 256 + 128 + a] = __float2half(acc);               // bottom (Wpu^T)
    if (a == 0) {
        float b = 0.f;
        #pragma unroll 8
        for (int k = 0; k < DIM; ++k)
            b += bphi[k] * Wu[(DIM + k) * DIM + j];
        bpu[j] = b;
    }
}

// ---------------------------------------------------------------------------
// Node GEMM via MFMA (fused with x->fp16 conversion):
//   [A''|B''] = fp16(x @ WABth^T + [bA|0]);  xh = fp16(x) stored by wave 0.
// ---------------------------------------------------------------------------
__global__ __launch_bounds__(256) void k_node_mfma(
    const float* __restrict__ x, const __half* __restrict__ WABth,
    const float* __restrict__ bA,
    __half* __restrict__ A, __half* __restrict__ Bv, __half* __restrict__ xh)
{
    __shared__ __half tile[64][264];   // 64 rows x 256 cols, +8 pad
    const int t    = threadIdx.x;
    const int wv   = t >> 6;
    const int lane = t & 63;
    const int n16  = lane & 15;
    const int quad = lane >> 4;
    const int m0   = blockIdx.x * 64;

    f32x4 acc[4][4];
    #pragma unroll
    for (int mt = 0; mt < 4; ++mt)
        #pragma unroll
        for (int nt = 0; nt < 4; ++nt)
            acc[mt][nt] = (f32x4){0.f, 0.f, 0.f, 0.f};

    int rowm[4];
    #pragma unroll
    for (int mt = 0; mt < 4; ++mt)
        rowm[mt] = min(m0 + mt * 16 + n16, NN - 1);

    #pragma unroll
    for (int ks = 0; ks < 4; ++ks) {
        const int ko = ks * 32 + quad * 8;
        f16x8 bf[4];
        #pragma unroll
        for (int nt = 0; nt < 4; ++nt) {
            const int c = wv * 64 + nt * 16 + n16;
            bf[nt] = *(const f16x8*)(WABth + c * DIM + ko);
        }
        #pragma unroll
        for (int mt = 0; mt < 4; ++mt) {
            const float4 xa = *(const float4*)(x + (size_t)rowm[mt] * DIM + ko);
            const float4 xb = *(const float4*)(x + (size_t)rowm[mt] * DIM + ko + 4);
            f16x8 af;
            af[0] = (_Float16)xa.x; af[1] = (_Float16)xa.y;
            af[2] = (_Float16)xa.z; af[3] = (_Float16)xa.w;
            af[4] = (_Float16)xb.x; af[5] = (_Float16)xb.y;
            af[6] = (_Float16)xb.z; af[7] = (_Float16)xb.w;
            if (wv == 0)   // wave 0 covers every (row, slice) exactly once
                *(f16x8*)(xh + (size_t)rowm[mt] * DIM + ko) = af;
            #pragma unroll
            for (int nt = 0; nt < 4; ++nt)
                acc[mt][nt] = __builtin_amdgcn_mfma_f32_16x16x32_f16(
                    af, bf[nt], acc[mt][nt], 0, 0, 0);
        }
    }

    // epilogue: +bias, fp16, LDS transpose
    #pragma unroll
    for (int nt = 0; nt < 4; ++nt) {
        const int c = wv * 64 + nt * 16 + n16;
        const float bias = (c < 128) ? bA[c] : 0.f;
        #pragma unroll
        for (int mt = 0; mt < 4; ++mt)
            #pragma unroll
            for (int reg = 0; reg < 4; ++reg)
                tile[mt * 16 + quad * 4 + reg][c] =
                    __float2half(acc[mt][nt][reg] + bias);
    }
    __syncthreads();

    // coalesced read-out: 2048 chunks of 16 B
    #pragma unroll
    for (int i = 0; i < 8; ++i) {
        const int chunk = t + i * 256;
        const int row = chunk >> 5;
        const int o   = (chunk & 31) * 8;   // half index 0..255
        if (m0 + row < NN) {
            const uint4 v = *(const uint4*)&tile[row][o];
            if (o < 128) *(uint4*)(A  + (size_t)(m0 + row) * DIM + o)       = v;
            else         *(uint4*)(Bv + (size_t)(m0 + row) * DIM + o - 128) = v;
        }
    }
}

// ---------------------------------------------------------------------------
// Gate kernel: 8 edges/wave — 4 slots x 16 lanes, 2 edges per slot.
// ---------------------------------------------------------------------------
__global__ __launch_bounds__(256) void k_gate(
    const int*   __restrict__ ei,  const float* __restrict__ ew,
    const float* __restrict__ ef,
    const __half* __restrict__ A,  const __half* __restrict__ Bv,
    const float* __restrict__ w0p, const float* __restrict__ w1p,
    const float* __restrict__ Wg2, const float* __restrict__ bg2,
    int* __restrict__ deg, int2* __restrict__ pairs)
{
    const int t    = threadIdx.x;
    const int lane = t & 63;
    const int sub  = lane >> 4;
    const int sl   = lane & 15;
    const int c8   = sl * 8;
    const int e0   = (blockIdx.x * 4 + (t >> 6)) * 8 + sub * 2;   // even

    const F8 WG = *(const F8*)(Wg2 + c8);
    const F8 W0 = *(const F8*)(w0p + c8);
    const F8 W1 = *(const F8*)(w1p + c8);
    const float bg2v = bg2[0];
    const float* w0 = (const float*)&W0;
    const float* w1 = (const float*)&W1;
    const float* wg = (const float*)&WG;

    const int2   srcs = *(const int2*)(ei + e0);
    const int2   dsts = *(const int2*)(ei + NE + e0);
    const float4 efv  = *(const float4*)(ef + 2 * e0);
    const float2 ewv  = *(const float2*)(ew + e0);

    const H8 a0 = *(const H8*)(A  + (size_t)dsts.x * DIM + c8);
    const H8 b0 = *(const H8*)(Bv + (size_t)srcs.x * DIM + c8);
    const H8 a1 = *(const H8*)(A  + (size_t)dsts.y * DIM + c8);
    const H8 b1 = *(const H8*)(Bv + (size_t)srcs.y * DIM + c8);

    float p0 = 0.f, p1 = 0.f;
    #pragma unroll
    for (int i = 0; i < 4; ++i) {
        const float2 s0 = __half22float2(__hadd2(a0.h[i], b0.h[i]));
        const float2 s1 = __half22float2(__hadd2(a1.h[i], b1.h[i]));
        const int c0 = 2 * i, c1 = 2 * i + 1;
        float h;
        h = s0.x + efv.x * w0[c0] + efv.y * w1[c0];
        p0 = __builtin_fmaf(gelu_fast(h), wg[c0], p0);
        h = s0.y + efv.x * w0[c1] + efv.y * w1[c1];
        p0 = __builtin_fmaf(gelu_fast(h), wg[c1], p0);
        h = s1.x + efv.z * w0[c0] + efv.w * w1[c0];
        p1 = __builtin_fmaf(gelu_fast(h), wg[c0], p1);
        h = s1.y + efv.z * w0[c1] + efv.w * w1[c1];
        p1 = __builtin_fmaf(gelu_fast(h), wg[c1], p1);
    }
    #pragma unroll
    for (int off = 1; off < 16; off <<= 1) {
        p0 += __shfl_xor(p0, off, 64);
        p1 += __shfl_xor(p1, off, 64);
    }

    if (sl == 0) {
        const float coef0 = ewv.x * sigmoid_fast(p0 + bg2v);
        const float coef1 = ewv.y * sigmoid_fast(p1 + bg2v);
        const int pos0 = atomicAdd(&deg[dsts.x], 1);
        if (pos0 < CAP)
            pairs[(size_t)dsts.x * CAP + pos0] = make_int2(srcs.x, __float_as_int(coef0));
        const int pos1 = atomicAdd(&deg[dsts.y], 1);
        if (pos1 < CAP)
            pairs[(size_t)dsts.y * CAP + pos1] = make_int2(srcs.y, __float_as_int(coef1));
    }
}

// ---------------------------------------------------------------------------
// Fused aggregation + update. Block = 256 thr = 4 waves, 64 nodes.
//   Phase 0: coalesced xh tile -> LDS (A-operand + residual source).
//   Phase 1: per 16-lane slot, aggregate FOUR nodes INTERLEAVED (4x MLP,
//            ~3x shorter dependent-load chain) into LDS (fp16) + sc into LDS.
//   Phase 2: MFMA h = [xt|at] @ Wct^T + bu + sc*bpu; y = xt + GELU(h);
//            out = LN(y), in-register stats.
// ---------------------------------------------------------------------------
__global__ __launch_bounds__(256) void k_agg_update(
    const int* __restrict__ deg, const int2* __restrict__ pairs,
    const __half* __restrict__ xh, const __half* __restrict__ Wct,
    const float* __restrict__ bu, const float* __restrict__ bpu,
    const float* __restrict__ lng, const float* __restrict__ lnb,
    float* __restrict__ out)
{
    __shared__ __half xt[64][136];   // x tile fp16, +8 pad (17.4 KB)
    __shared__ __half at[64][136];   // agg tile fp16 (17.4 KB)
    __shared__ float sct[64];

    const int t    = threadIdx.x;
    const int wv   = t >> 6;
    const int lane = t & 63;
    const int n16  = lane & 15;
    const int quad = lane >> 4;
    const int m0   = blockIdx.x * 64;

    // ---- Phase 1 prologue: issue deg loads first (overlap with tile load) --
    const int slot = t >> 4;
    const int sl   = t & 15;
    const int c8   = sl * 8;

    int    dd[4];
    size_t bb[4];
    #pragma unroll
    for (int r = 0; r < 4; ++r) {
        const int lr = r * 16 + slot;
        const int nc = min(m0 + lr, NN - 1);
        dd[r] = min(deg[nc], CAP);
        bb[r] = (size_t)nc * CAP;
    }

    // ---- Phase 0: cooperative xh tile load (coalesced f16x8) ----
    #pragma unroll
    for (int i = 0; i < 4; ++i) {
        const int idx = i * 256 + t;          // 8-half chunk id
        const int row = idx >> 4;             // 16 chunks per row
        const int col = (idx & 15) * 8;
        const int grow = min(m0 + row, NN - 1);
        *(f16x8*)&xt[row][col] = *(const f16x8*)(xh + (size_t)grow * DIM + col);
    }

    // ---- Phase 1: interleaved aggregation across the slot's 4 nodes ----
    float acc[4][8];
    float scn[4] = {0.f, 0.f, 0.f, 0.f};
    #pragma unroll
    for (int r = 0; r < 4; ++r)
        #pragma unroll
        for (int i = 0; i < 8; ++i) acc[r][i] = 0.f;

    const int dmax = max(max(dd[0], dd[1]), max(dd[2], dd[3]));

    for (int j = 0; j < dmax; j += 2) {
        // 4 independent vectorized pair loads (2 pairs each; always in-bounds:
        // j+1 < CAP and the pairs buffer is fully allocated NN*CAP)
        int4 pq[4];
        #pragma unroll
        for (int r = 0; r < 4; ++r)
            pq[r] = *(const int4*)(&pairs[bb[r] + j]);

        // branchless validity: invalid -> gather row 0 (L1-hot) with coef 0
        int   ix[8];
        float cf[8];
        #pragma unroll
        for (int r = 0; r < 4; ++r) {
            const bool v0 = (j     < dd[r]);
            const bool v1 = (j + 1 < dd[r]);
            ix[2 * r]     = v0 ? pq[r].x : 0;
            cf[2 * r]     = v0 ? __int_as_float(pq[r].y) : 0.f;
            ix[2 * r + 1] = v1 ? pq[r].z : 0;
            cf[2 * r + 1] = v1 ? __int_as_float(pq[r].w) : 0.f;
        }

        // 8 independent row gathers in flight
        H8 xv[8];
        #pragma unroll
        for (int q = 0; q < 8; ++q)
            xv[q] = *(const H8*)(xh + (size_t)ix[q] * DIM + c8);

        #pragma unroll
        for (int r = 0; r < 4; ++r) {
            #pragma unroll
            for (int k = 0; k < 2; ++k) {
                const int   q  = 2 * r + k;
                const float c  = cf[q];
                #pragma unroll
                for (int i = 0; i < 4; ++i) {
                    const float2 f = __half22float2(xv[q].h[i]);
                    acc[r][2 * i]     = __builtin_fmaf(c, f.x, acc[r][2 * i]);
                    acc[r][2 * i + 1] = __builtin_fmaf(c, f.y, acc[r][2 * i + 1]);
                }
                scn[r] += c;
            }
        }
    }

    #pragma unroll
    for (int r = 0; r < 4; ++r) {
        const int lr = r * 16 + slot;
        f16x8 hv;
        #pragma unroll
        for (int i = 0; i < 8; ++i) hv[i] = (_Float16)acc[r][i];
        *(f16x8*)&at[lr][c8] = hv;
        if (sl == 0) sct[lr] = scn[r];
    }
    __syncthreads();

    // ---- Phase 2: MFMA update for wave's 16 rows ----
    f32x4 acc2[8];
    #pragma unroll
    for (int nt = 0; nt < 8; ++nt) acc2[nt] = (f32x4){0.f, 0.f, 0.f, 0.f};

    const int rloc = wv * 16 + n16;           // A-fragment local row
    #pragma unroll
    for (int ks = 0; ks < 4; ++ks) {
        const int ko = ks * 32 + quad * 8;
        const f16x8 af = *(const f16x8*)&xt[rloc][ko];
        #pragma unroll
        for (int nt = 0; nt < 8; ++nt) {
            const f16x8 bf = *(const f16x8*)(Wct + (nt * 16 + n16) * 256 + ko);
            acc2[nt] = __builtin_amdgcn_mfma_f32_16x16x32_f16(af, bf, acc2[nt], 0, 0, 0);
        }
    }
    #pragma unroll
    for (int ks = 0; ks < 4; ++ks) {
        const int ko = ks * 32 + quad * 8;
        const f16x8 af = *(const f16x8*)&at[rloc][ko];
        #pragma unroll
        for (int nt = 0; nt < 8; ++nt) {
            const f16x8 bf = *(const f16x8*)(Wct + (nt * 16 + n16) * 256 + 128 + ko);
            acc2[nt] = __builtin_amdgcn_mfma_f32_16x16x32_f16(af, bf, acc2[nt], 0, 0, 0);
        }
    }

    // ---- epilogue ----
    int   rl[4];
    float scv[4];
    #pragma unroll
    for (int reg = 0; reg < 4; ++reg) {
        rl[reg]  = wv * 16 + quad * 4 + reg;   // local row
        scv[reg] = sct[rl[reg]];
    }

    float yv[8][4];
    float s[4]  = {0.f, 0.f, 0.f, 0.f};
    float ss[4] = {0.f, 0.f, 0.f, 0.f};

    #pragma unroll
    for (int nt = 0; nt < 8; ++nt) {
        const int c = nt * 16 + n16;
        const float buv = bu[c], bpv = bpu[c];
        #pragma unroll
        for (int reg = 0; reg < 4; ++reg) {
            float h = acc2[nt][reg] + buv + scv[reg] * bpv;
            h = gelu_fast(h);
            const float xv = __half2float(xt[rl[reg]][c]);   // residual from LDS
            const float y = xv + h;
            yv[nt][reg] = y;
            s[reg]  += y;
            ss[reg] += y * y;
        }
    }

    #pragma unroll
    for (int reg = 0; reg < 4; ++reg) {
        #pragma unroll
        for (int off = 1; off < 16; off <<= 1) {
            s[reg]  += __shfl_xor(s[reg],  off, 64);
            ss[reg] += __shfl_xor(ss[reg], off, 64);
        }
    }

    float mu[4], rs[4];
    #pragma unroll
    for (int reg = 0; reg < 4; ++reg) {
        mu[reg] = s[reg] * (1.f / DIM);
        const float var = ss[reg] * (1.f / DIM) - mu[reg] * mu[reg];
        rs[reg] = rsqrtf(var + EPS);
    }

    #pragma unroll
    for (int nt = 0; nt < 8; ++nt) {
        const int c = nt * 16 + n16;
        const float gg = lng[c], bb2 = lnb[c];
        #pragma unroll
        for (int reg = 0; reg < 4; ++reg) {
            const int grow = m0 + rl[reg];
            if (grow < NN)
                __builtin_nontemporal_store(
                    (yv[nt][reg] - mu[reg]) * rs[reg] * gg + bb2,
                    &out[(size_t)grow * DIM + c]);
        }
    }
}

// ---------------------------------------------------------------------------
extern "C" void kernel_launch(void* const* d_in, const int* in_sizes, int n_in,
                              void* d_out, int out_size, void* d_ws, size_t ws_size,
                              hipStream_t stream)
{
    const float* x    = (const float*)d_in[0];
    const int*   ei   = (const int*)  d_in[1];
    const float* ew   = (const float*)d_in[2];
    const float* ef   = (const float*)d_in[3];
    const float* Wphi = (const float*)d_in[5];
    const float* bphi = (const float*)d_in[6];
    const float* Wg1  = (const float*)d_in[7];
    const float* bg1  = (const float*)d_in[8];
    const float* bng  = (const float*)d_in[9];
    const float* bnb  = (const float*)d_in[10];
    const float* bnm  = (const float*)d_in[11];
    const float* bnv  = (const float*)d_in[12];
    const float* Wg2  = (const float*)d_in[13];
    const float* bg2  = (const float*)d_in[14];
    const float* Wu   = (const float*)d_in[15];
    const float* bu   = (const float*)d_in[16];
    const float* lng  = (const float*)d_in[17];
    const float* lnb  = (const float*)d_in[18];

    float* out = (float*)d_out;

    char* wsb = (char*)d_ws;
    size_t off = 0;
    auto carve = [&](size_t bytes) -> void* {
        void* p = wsb + off;
        off += (bytes + 255) & ~(size_t)255;
        return p;
    };
    __half* xh    = (__half*)carve((size_t)NN * DIM * 2);
    __half* A     = (__half*)carve((size_t)NN * DIM * 2);
    __half* Bv    = (__half*)carve((size_t)NN * DIM * 2);
    __half* WABth = (__half*)carve(256 * DIM * 2);
    __half* Wct   = (__half*)carve(DIM * 256 * 2);
    float*  bA    = (float*) carve(DIM * 4);
    float*  w0p   = (float*) carve(DIM * 4);
    float*  w1p   = (float*) carve(DIM * 4);
    float*  bpu   = (float*) carve(DIM * 4);
    int*    deg   = (int*)   carve((size_t)NN * 4);
    int2*   pairs = (int2*)  carve((size_t)NN * CAP * 8);

    hipMemsetAsync(deg, 0, (size_t)NN * 4, stream);

    k_prep_scale<<<128, 256, 0, stream>>>(Wg1, bg1, bng, bnb, bnm, bnv,
                                          WABth, bA, w0p, w1p);
    k_prep_wpu<<<128, 128, 0, stream>>>(Wphi, bphi, Wu, Wct, bpu);
    k_node_mfma<<<(NN + 63) / 64, 256, 0, stream>>>(x, WABth, bA, A, Bv, xh);
    k_gate<<<NE / 32, 256, 0, stream>>>(ei, ew, ef, A, Bv, w0p, w1p, Wg2, bg2,
                                        deg, pairs);
    k_agg_update<<<(NN + 63) / 64, 256, 0, stream>>>(deg, pairs, xh, Wct,
                                                     bu, bpu, lng, lnb, out);
}

// Round 2
// 263.575 us; speedup vs baseline: 1.1324x; 1.0495x over previous
//
#include <hip/hip_runtime.h>
#include <hip/hip_fp16.h>
#include <math.h>

#define DIM 128
#define NN 50000
#define NE 600000
#define EPS 1e-5f
#define CAP 64   // per-dst bucket capacity; P(Poisson(12) > 64) ~ 5e-26

struct H8 { __half2 h[4]; };   // 16 B of fp16 channels
struct F8 { float4 a, b; };    // 32 B of fp32 channels

typedef _Float16 f16x8 __attribute__((ext_vector_type(8)));
typedef float    f32x4 __attribute__((ext_vector_type(4)));

// fast GELU (tanh form), |err| < ~7e-4 absolute
__device__ __forceinline__ float gelu_fast(float x) {
    const float c1 = 2.3022085f;   // 0.7978845608 * 2 * log2(e)
    const float c2 = 0.1029437f;   // c1 * 0.044715
    const float x2 = x * x;
    const float z  = x * __builtin_fmaf(c2, x2, c1);
    const float u  = __builtin_amdgcn_exp2f(z);
    const float r  = __builtin_amdgcn_rcpf(1.f + u);
    return __builtin_fmaf(-x, r, x);
}

__device__ __forceinline__ float sigmoid_fast(float y) {
    const float u = __builtin_amdgcn_exp2f(-1.4426950409f * y);
    return __builtin_amdgcn_rcpf(1.f + u);
}

// ---------------------------------------------------------------------------
// Prep 1: fold BN scale into gate layer-1 weights; emit fragment-ready
// fp16 transposed weights WABth[c][k] (c=0..255 over [WA|WB], k=0..127).
// ---------------------------------------------------------------------------
__global__ __launch_bounds__(256) void k_prep_scale(
    const float* __restrict__ Wg1, const float* __restrict__ bg1,
    const float* __restrict__ bng, const float* __restrict__ bnb,
    const float* __restrict__ bnm, const float* __restrict__ bnv,
    __half* __restrict__ WABth, float* __restrict__ bA,
    float* __restrict__ w0p, float* __restrict__ w1p)
{
    const int k = blockIdx.x;      // 0..127
    const int t = threadIdx.x;     // 0..255 (fused col)
    const int c = t & 127;
    const float s = bng[c] * rsqrtf(bnv[c] + EPS);
    const float w = (t < 128) ? Wg1[k * DIM + c] : Wg1[(DIM + k) * DIM + c];
    WABth[t * DIM + k] = __float2half(w * s);
    if (k == 0 && t < 128) {
        const float tt = bnb[c] - bnm[c] * s;
        bA[c]  = bg1[c] * s + tt;
        w0p[c] = Wg1[256 * DIM + c] * s;
        w1p[c] = Wg1[257 * DIM + c] * s;
    }
}

// ---------------------------------------------------------------------------
// Prep 2: fragment-ready update weights Wct[j][k] (j=0..127, k=0..255):
//   k<128 -> Wu_top[k][j];  k>=128 -> Wpu[k-128][j] = (Wphi @ Wu_bot)[k-128][j]
// plus bpu[j] = bphi @ Wu_bot.
// ---------------------------------------------------------------------------
__global__ __launch_bounds__(128) void k_prep_wpu(
    const float* __restrict__ Wphi, const float* __restrict__ bphi,
    const float* __restrict__ Wu,
    __half* __restrict__ Wct, float* __restrict__ bpu)
{
    const int a = blockIdx.x;      // 0..127
    const int j = threadIdx.x;     // 0..127
    float acc = 0.f;
    #pragma unroll 8
    for (int k = 0; k < DIM; ++k)
        acc += Wphi[a * DIM + k] * Wu[(DIM + k) * DIM + j];
    Wct[j * 256 + a]       = __float2half(Wu[a * DIM + j]);   // top (Wu_top^T)
    Wct[j * 256 + 128 + a] = __float2half(acc);               // bottom (Wpu^T)
    if (a == 0) {
        float b = 0.f;
        #pragma unroll 8
        for (int k = 0; k < DIM; ++k)
            b += bphi[k] * Wu[(DIM + k) * DIM + j];
        bpu[j] = b;
    }
}

// ---------------------------------------------------------------------------
// Node GEMM via MFMA (fused with x->fp16 conversion):
//   [A''|B''] = fp16(x @ WABth^T + [bA|0]);  xh = fp16(x) stored by wave 0.
// ---------------------------------------------------------------------------
__global__ __launch_bounds__(256) void k_node_mfma(
    const float* __restrict__ x, const __half* __restrict__ WABth,
    const float* __restrict__ bA,
    __half* __restrict__ A, __half* __restrict__ Bv, __half* __restrict__ xh)
{
    __shared__ __half tile[64][264];   // 64 rows x 256 cols, +8 pad
    const int t    = threadIdx.x;
    const int wv   = t >> 6;
    const int lane = t & 63;
    const int n16  = lane & 15;
    const int quad = lane >> 4;
    const int m0   = blockIdx.x * 64;

    f32x4 acc[4][4];
    #pragma unroll
    for (int mt = 0; mt < 4; ++mt)
        #pragma unroll
        for (int nt = 0; nt < 4; ++nt)
            acc[mt][nt] = (f32x4){0.f, 0.f, 0.f, 0.f};

    int rowm[4];
    #pragma unroll
    for (int mt = 0; mt < 4; ++mt)
        rowm[mt] = min(m0 + mt * 16 + n16, NN - 1);

    #pragma unroll
    for (int ks = 0; ks < 4; ++ks) {
        const int ko = ks * 32 + quad * 8;
        f16x8 bf[4];
        #pragma unroll
        for (int nt = 0; nt < 4; ++nt) {
            const int c = wv * 64 + nt * 16 + n16;
            bf[nt] = *(const f16x8*)(WABth + c * DIM + ko);
        }
        #pragma unroll
        for (int mt = 0; mt < 4; ++mt) {
            const float4 xa = *(const float4*)(x + (size_t)rowm[mt] * DIM + ko);
            const float4 xb = *(const float4*)(x + (size_t)rowm[mt] * DIM + ko + 4);
            f16x8 af;
            af[0] = (_Float16)xa.x; af[1] = (_Float16)xa.y;
            af[2] = (_Float16)xa.z; af[3] = (_Float16)xa.w;
            af[4] = (_Float16)xb.x; af[5] = (_Float16)xb.y;
            af[6] = (_Float16)xb.z; af[7] = (_Float16)xb.w;
            if (wv == 0)   // wave 0 covers every (row, slice) exactly once
                *(f16x8*)(xh + (size_t)rowm[mt] * DIM + ko) = af;
            #pragma unroll
            for (int nt = 0; nt < 4; ++nt)
                acc[mt][nt] = __builtin_amdgcn_mfma_f32_16x16x32_f16(
                    af, bf[nt], acc[mt][nt], 0, 0, 0);
        }
    }

    // epilogue: +bias, fp16, LDS transpose
    #pragma unroll
    for (int nt = 0; nt < 4; ++nt) {
        const int c = wv * 64 + nt * 16 + n16;
        const float bias = (c < 128) ? bA[c] : 0.f;
        #pragma unroll
        for (int mt = 0; mt < 4; ++mt)
            #pragma unroll
            for (int reg = 0; reg < 4; ++reg)
                tile[mt * 16 + quad * 4 + reg][c] =
                    __float2half(acc[mt][nt][reg] + bias);
    }
    __syncthreads();

    // coalesced read-out: 2048 chunks of 16 B
    #pragma unroll
    for (int i = 0; i < 8; ++i) {
        const int chunk = t + i * 256;
        const int row = chunk >> 5;
        const int o   = (chunk & 31) * 8;   // half index 0..255
        if (m0 + row < NN) {
            const uint4 v = *(const uint4*)&tile[row][o];
            if (o < 128) *(uint4*)(A  + (size_t)(m0 + row) * DIM + o)       = v;
            else         *(uint4*)(Bv + (size_t)(m0 + row) * DIM + o - 128) = v;
        }
    }
}

// ---------------------------------------------------------------------------
// Gate kernel: 8 edges/wave — 4 slots x 16 lanes, 2 edges per slot.
// ---------------------------------------------------------------------------
__global__ __launch_bounds__(256) void k_gate(
    const int*   __restrict__ ei,  const float* __restrict__ ew,
    const float* __restrict__ ef,
    const __half* __restrict__ A,  const __half* __restrict__ Bv,
    const float* __restrict__ w0p, const float* __restrict__ w1p,
    const float* __restrict__ Wg2, const float* __restrict__ bg2,
    int* __restrict__ deg, int2* __restrict__ pairs)
{
    const int t    = threadIdx.x;
    const int lane = t & 63;
    const int sub  = lane >> 4;
    const int sl   = lane & 15;
    const int c8   = sl * 8;
    const int e0   = (blockIdx.x * 4 + (t >> 6)) * 8 + sub * 2;   // even

    const F8 WG = *(const F8*)(Wg2 + c8);
    const F8 W0 = *(const F8*)(w0p + c8);
    const F8 W1 = *(const F8*)(w1p + c8);
    const float bg2v = bg2[0];
    const float* w0 = (const float*)&W0;
    const float* w1 = (const float*)&W1;
    const float* wg = (const float*)&WG;

    const int2   srcs = *(const int2*)(ei + e0);
    const int2   dsts = *(const int2*)(ei + NE + e0);
    const float4 efv  = *(const float4*)(ef + 2 * e0);
    const float2 ewv  = *(const float2*)(ew + e0);

    const H8 a0 = *(const H8*)(A  + (size_t)dsts.x * DIM + c8);
    const H8 b0 = *(const H8*)(Bv + (size_t)srcs.x * DIM + c8);
    const H8 a1 = *(const H8*)(A  + (size_t)dsts.y * DIM + c8);
    const H8 b1 = *(const H8*)(Bv + (size_t)srcs.y * DIM + c8);

    float p0 = 0.f, p1 = 0.f;
    #pragma unroll
    for (int i = 0; i < 4; ++i) {
        const float2 s0 = __half22float2(__hadd2(a0.h[i], b0.h[i]));
        const float2 s1 = __half22float2(__hadd2(a1.h[i], b1.h[i]));
        const int c0 = 2 * i, c1 = 2 * i + 1;
        float h;
        h = s0.x + efv.x * w0[c0] + efv.y * w1[c0];
        p0 = __builtin_fmaf(gelu_fast(h), wg[c0], p0);
        h = s0.y + efv.x * w0[c1] + efv.y * w1[c1];
        p0 = __builtin_fmaf(gelu_fast(h), wg[c1], p0);
        h = s1.x + efv.z * w0[c0] + efv.w * w1[c0];
        p1 = __builtin_fmaf(gelu_fast(h), wg[c0], p1);
        h = s1.y + efv.z * w0[c1] + efv.w * w1[c1];
        p1 = __builtin_fmaf(gelu_fast(h), wg[c1], p1);
    }
    #pragma unroll
    for (int off = 1; off < 16; off <<= 1) {
        p0 += __shfl_xor(p0, off, 64);
        p1 += __shfl_xor(p1, off, 64);
    }

    if (sl == 0) {
        const float coef0 = ewv.x * sigmoid_fast(p0 + bg2v);
        const float coef1 = ewv.y * sigmoid_fast(p1 + bg2v);
        const int pos0 = atomicAdd(&deg[dsts.x], 1);
        if (pos0 < CAP)
            pairs[(size_t)dsts.x * CAP + pos0] = make_int2(srcs.x, __float_as_int(coef0));
        const int pos1 = atomicAdd(&deg[dsts.y], 1);
        if (pos1 < CAP)
            pairs[(size_t)dsts.y * CAP + pos1] = make_int2(srcs.y, __float_as_int(coef1));
    }
}

// ---------------------------------------------------------------------------
// Fused aggregation + update. Block = 64 thr = 1 wave, 16 nodes.
//   (Small blocks: grid 3125 -> ~12 blocks/CU, fine drain granularity;
//    barrier imbalance only over the block's own 16 nodes.)
//   Phase 0: coalesced xh tile -> LDS (A-operand + residual source).
//   Phase 1: per 16-lane slot, aggregate FOUR nodes INTERLEAVED, edge loop
//            unrolled x4 -> 16 independent gathers in flight per slot.
//   Phase 2: MFMA h = [xt|at] @ Wct^T + bu + sc*bpu; y = xt + GELU(h);
//            out = LN(y), in-register stats.
// ---------------------------------------------------------------------------
__global__ __launch_bounds__(64, 3) void k_agg_update(
    const int* __restrict__ deg, const int2* __restrict__ pairs,
    const __half* __restrict__ xh, const __half* __restrict__ Wct,
    const float* __restrict__ bu, const float* __restrict__ bpu,
    const float* __restrict__ lng, const float* __restrict__ lnb,
    float* __restrict__ out)
{
    __shared__ __half xt[16][136];   // x tile fp16, +8 pad (4.35 KB)
    __shared__ __half at[16][136];   // agg tile fp16 (4.35 KB)
    __shared__ float sct[16];

    const int t    = threadIdx.x;    // 0..63
    const int n16  = t & 15;
    const int quad = t >> 4;         // 0..3
    const int m0   = blockIdx.x * 16;

    // ---- Phase 1 prologue: issue deg loads first (overlap with tile load) --
    const int slot = t >> 4;         // 0..3
    const int sl   = t & 15;
    const int c8   = sl * 8;

    int    dd[4];
    size_t bb[4];
    #pragma unroll
    for (int r = 0; r < 4; ++r) {
        const int lr = r * 4 + slot;
        const int nc = min(m0 + lr, NN - 1);
        dd[r] = min(deg[nc], CAP);
        bb[r] = (size_t)nc * CAP;
    }

    // ---- Phase 0: cooperative xh tile load (coalesced f16x8) ----
    #pragma unroll
    for (int i = 0; i < 4; ++i) {
        const int idx = i * 64 + t;           // 8-half chunk id
        const int row = idx >> 4;             // 16 chunks per row
        const int col = (idx & 15) * 8;
        const int grow = min(m0 + row, NN - 1);
        *(f16x8*)&xt[row][col] = *(const f16x8*)(xh + (size_t)grow * DIM + col);
    }

    // ---- Phase 1: interleaved aggregation, 4 nodes x 4 edges per step ----
    float acc[4][8];
    float scn[4] = {0.f, 0.f, 0.f, 0.f};
    #pragma unroll
    for (int r = 0; r < 4; ++r)
        #pragma unroll
        for (int i = 0; i < 8; ++i) acc[r][i] = 0.f;

    const int dmax = max(max(dd[0], dd[1]), max(dd[2], dd[3]));

    for (int j = 0; j < dmax; j += 4) {
        // 8 independent vectorized pair loads (2 pairs each). The +2 read can
        // overhang a bucket by <=2 entries -> masked below; pairs allocation
        // carries 256 B of tail slack so it is always in-bounds.
        int4 pq0[4], pq1[4];
        #pragma unroll
        for (int r = 0; r < 4; ++r) {
            pq0[r] = *(const int4*)(&pairs[bb[r] + j]);
            pq1[r] = *(const int4*)(&pairs[bb[r] + j + 2]);
        }

        // branchless validity: invalid -> gather row 0 (L1-hot) with coef 0
        int   ix[16];
        float cf[16];
        #pragma unroll
        for (int r = 0; r < 4; ++r) {
            const int q = 4 * r;
            const bool v0 = (j     < dd[r]);
            const bool v1 = (j + 1 < dd[r]);
            const bool v2 = (j + 2 < dd[r]);
            const bool v3 = (j + 3 < dd[r]);
            ix[q]     = v0 ? pq0[r].x : 0;
            cf[q]     = v0 ? __int_as_float(pq0[r].y) : 0.f;
            ix[q + 1] = v1 ? pq0[r].z : 0;
            cf[q + 1] = v1 ? __int_as_float(pq0[r].w) : 0.f;
            ix[q + 2] = v2 ? pq1[r].x : 0;
            cf[q + 2] = v2 ? __int_as_float(pq1[r].y) : 0.f;
            ix[q + 3] = v3 ? pq1[r].z : 0;
            cf[q + 3] = v3 ? __int_as_float(pq1[r].w) : 0.f;
        }

        // 16 independent row gathers in flight
        H8 xv[16];
        #pragma unroll
        for (int q = 0; q < 16; ++q)
            xv[q] = *(const H8*)(xh + (size_t)ix[q] * DIM + c8);

        #pragma unroll
        for (int r = 0; r < 4; ++r) {
            #pragma unroll
            for (int k = 0; k < 4; ++k) {
                const int   q = 4 * r + k;
                const float c = cf[q];
                #pragma unroll
                for (int i = 0; i < 4; ++i) {
                    const float2 f = __half22float2(xv[q].h[i]);
                    acc[r][2 * i]     = __builtin_fmaf(c, f.x, acc[r][2 * i]);
                    acc[r][2 * i + 1] = __builtin_fmaf(c, f.y, acc[r][2 * i + 1]);
                }
                scn[r] += c;
            }
        }
    }

    #pragma unroll
    for (int r = 0; r < 4; ++r) {
        const int lr = r * 4 + slot;
        f16x8 hv;
        #pragma unroll
        for (int i = 0; i < 8; ++i) hv[i] = (_Float16)acc[r][i];
        *(f16x8*)&at[lr][c8] = hv;
        if (sl == 0) sct[lr] = scn[r];
    }
    __syncthreads();

    // ---- Phase 2: MFMA update for the wave's 16 rows ----
    f32x4 acc2[8];
    #pragma unroll
    for (int nt = 0; nt < 8; ++nt) acc2[nt] = (f32x4){0.f, 0.f, 0.f, 0.f};

    const int rloc = n16;                     // A-fragment local row
    #pragma unroll
    for (int ks = 0; ks < 4; ++ks) {
        const int ko = ks * 32 + quad * 8;
        const f16x8 af = *(const f16x8*)&xt[rloc][ko];
        #pragma unroll
        for (int nt = 0; nt < 8; ++nt) {
            const f16x8 bf = *(const f16x8*)(Wct + (nt * 16 + n16) * 256 + ko);
            acc2[nt] = __builtin_amdgcn_mfma_f32_16x16x32_f16(af, bf, acc2[nt], 0, 0, 0);
        }
    }
    #pragma unroll
    for (int ks = 0; ks < 4; ++ks) {
        const int ko = ks * 32 + quad * 8;
        const f16x8 af = *(const f16x8*)&at[rloc][ko];
        #pragma unroll
        for (int nt = 0; nt < 8; ++nt) {
            const f16x8 bf = *(const f16x8*)(Wct + (nt * 16 + n16) * 256 + 128 + ko);
            acc2[nt] = __builtin_amdgcn_mfma_f32_16x16x32_f16(af, bf, acc2[nt], 0, 0, 0);
        }
    }

    // ---- epilogue ----
    int   rl[4];
    float scv[4];
    #pragma unroll
    for (int reg = 0; reg < 4; ++reg) {
        rl[reg]  = quad * 4 + reg;            // local row
        scv[reg] = sct[rl[reg]];
    }

    float yv[8][4];
    float s[4]  = {0.f, 0.f, 0.f, 0.f};
    float ss[4] = {0.f, 0.f, 0.f, 0.f};

    #pragma unroll
    for (int nt = 0; nt < 8; ++nt) {
        const int c = nt * 16 + n16;
        const float buv = bu[c], bpv = bpu[c];
        #pragma unroll
        for (int reg = 0; reg < 4; ++reg) {
            float h = acc2[nt][reg] + buv + scv[reg] * bpv;
            h = gelu_fast(h);
            const float xv = __half2float(xt[rl[reg]][c]);   // residual from LDS
            const float y = xv + h;
            yv[nt][reg] = y;
            s[reg]  += y;
            ss[reg] += y * y;
        }
    }

    #pragma unroll
    for (int reg = 0; reg < 4; ++reg) {
        #pragma unroll
        for (int off = 1; off < 16; off <<= 1) {
            s[reg]  += __shfl_xor(s[reg],  off, 64);
            ss[reg] += __shfl_xor(ss[reg], off, 64);
        }
    }

    float mu[4], rs[4];
    #pragma unroll
    for (int reg = 0; reg < 4; ++reg) {
        mu[reg] = s[reg] * (1.f / DIM);
        const float var = ss[reg] * (1.f / DIM) - mu[reg] * mu[reg];
        rs[reg] = rsqrtf(var + EPS);
    }

    #pragma unroll
    for (int nt = 0; nt < 8; ++nt) {
        const int c = nt * 16 + n16;
        const float gg = lng[c], bb2 = lnb[c];
        #pragma unroll
        for (int reg = 0; reg < 4; ++reg) {
            const int grow = m0 + rl[reg];
            if (grow < NN)
                __builtin_nontemporal_store(
                    (yv[nt][reg] - mu[reg]) * rs[reg] * gg + bb2,
                    &out[(size_t)grow * DIM + c]);
        }
    }
}

// ---------------------------------------------------------------------------
extern "C" void kernel_launch(void* const* d_in, const int* in_sizes, int n_in,
                              void* d_out, int out_size, void* d_ws, size_t ws_size,
                              hipStream_t stream)
{
    const float* x    = (const float*)d_in[0];
    const int*   ei   = (const int*)  d_in[1];
    const float* ew   = (const float*)d_in[2];
    const float* ef   = (const float*)d_in[3];
    const float* Wphi = (const float*)d_in[5];
    const float* bphi = (const float*)d_in[6];
    const float* Wg1  = (const float*)d_in[7];
    const float* bg1  = (const float*)d_in[8];
    const float* bng  = (const float*)d_in[9];
    const float* bnb  = (const float*)d_in[10];
    const float* bnm  = (const float*)d_in[11];
    const float* bnv  = (const float*)d_in[12];
    const float* Wg2  = (const float*)d_in[13];
    const float* bg2  = (const float*)d_in[14];
    const float* Wu   = (const float*)d_in[15];
    const float* bu   = (const float*)d_in[16];
    const float* lng  = (const float*)d_in[17];
    const float* lnb  = (const float*)d_in[18];

    float* out = (float*)d_out;

    char* wsb = (char*)d_ws;
    size_t off = 0;
    auto carve = [&](size_t bytes) -> void* {
        void* p = wsb + off;
        off += (bytes + 255) & ~(size_t)255;
        return p;
    };
    __half* xh    = (__half*)carve((size_t)NN * DIM * 2);
    __half* A     = (__half*)carve((size_t)NN * DIM * 2);
    __half* Bv    = (__half*)carve((size_t)NN * DIM * 2);
    __half* WABth = (__half*)carve(256 * DIM * 2);
    __half* Wct   = (__half*)carve(DIM * 256 * 2);
    float*  bA    = (float*) carve(DIM * 4);
    float*  w0p   = (float*) carve(DIM * 4);
    float*  w1p   = (float*) carve(DIM * 4);
    float*  bpu   = (float*) carve(DIM * 4);
    int*    deg   = (int*)   carve((size_t)NN * 4);
    int2*   pairs = (int2*)  carve((size_t)NN * CAP * 8 + 256);  // +tail slack

    hipMemsetAsync(deg, 0, (size_t)NN * 4, stream);

    k_prep_scale<<<128, 256, 0, stream>>>(Wg1, bg1, bng, bnb, bnm, bnv,
                                          WABth, bA, w0p, w1p);
    k_prep_wpu<<<128, 128, 0, stream>>>(Wphi, bphi, Wu, Wct, bpu);
    k_node_mfma<<<(NN + 63) / 64, 256, 0, stream>>>(x, WABth, bA, A, Bv, xh);
    k_gate<<<NE / 32, 256, 0, stream>>>(ei, ew, ef, A, Bv, w0p, w1p, Wg2, bg2,
                                        deg, pairs);
    k_agg_update<<<(NN + 15) / 16, 64, 0, stream>>>(deg, pairs, xh, Wct,
                                                    bu, bpu, lng, lnb, out);
}